// Round 11
// baseline (768.934 us; speedup 1.0000x reference)
//
#include <hip/hip_runtime.h>

// ---------------------------------------------------------------------------
// ConditionedLatentSDETransition - MI355X (round 25: single-barrier pipeline)
//
// r24 = 763us. DEEP (3-buffer, 1 barrier/iter) on fupd gained only ~4us ->
// K-loop latency exonerated for fupd; but x1t/x2g still pay 2 barriers +
// 1 lgkm drain per K-iter. This round: 2-buffer SINGLE-barrier scheme for
// x1t/x2g (stage-after-barrier, proven safe by the r24 DEEP argument:
// all waves' ds_reads of the previous tile retire before they reach the
// top-of-iter barrier, so the alt buffer is dead-on-arrival; per-wave
// vmcnt(0) before the barrier covers read-after-write). Saves one barrier
// + one lgkmcnt per iter with zero LDS growth (keeps 3 blk/CU).
// fupd keeps r24 DEEP=1 3-buffer. Numerics identical.
// ---------------------------------------------------------------------------

typedef unsigned short ushort_t;
typedef __bf16 bf16x8 __attribute__((ext_vector_type(8)));
typedef _Float16 f16x8 __attribute__((ext_vector_type(8)));
typedef float f32x4 __attribute__((ext_vector_type(4)));

__device__ __forceinline__ float bf2f(ushort_t s) {
  unsigned u = ((unsigned)s) << 16;
  return __uint_as_float(u);
}
__device__ __forceinline__ ushort_t f2bf(float f) {
  unsigned u = __float_as_uint(f);
  unsigned lsb = (u >> 16) & 1u;
  u += 0x7fffu + lsb;
  return (ushort_t)(u >> 16);
}
__device__ __forceinline__ float ldin(const void* p, size_t i, int f32) {
  return f32 ? ((const float*)p)[i] : bf2f(((const ushort_t*)p)[i]);
}
__device__ __forceinline__ void async16(const void* g, void* l) {
  __builtin_amdgcn_global_load_lds(
      (const __attribute__((address_space(1))) void*)g,
      (__attribute__((address_space(3))) void*)l, 16, 0, 0);
}

template <int N>
__device__ __forceinline__ void waitvm() {
  if constexpr (N == 0) {
    asm volatile("s_waitcnt vmcnt(0)" ::: "memory");
  } else if constexpr (N == 4) {
    asm volatile("s_waitcnt vmcnt(4)" ::: "memory");
  } else if constexpr (N == 6) {
    asm volatile("s_waitcnt vmcnt(6)" ::: "memory");
  }
  __builtin_amdgcn_sched_barrier(0);
}
__device__ __forceinline__ void waitlgkm0() {
  asm volatile("s_waitcnt lgkmcnt(0)" ::: "memory");
  __builtin_amdgcn_sched_barrier(0);
}

// Swizzled fragment read from a [rows][64] bf16 tile staged with source-side
// swizzle kc ^= (row&7). kb = bf16 offset in row, multiple of 8.
__device__ __forceinline__ bf16x8 lds_frag(const __bf16* T, int row, int kb) {
  const int byte = (row << 7) + ((((kb >> 3) ^ (row & 7))) << 4);
  return *(const bf16x8*)((const char*)T + byte);
}

// consts: [0]=h, [1]=sqrt_h, [2]=dt, [3]=f32flag
__global__ void k_detect(const void* __restrict__ eps, const void* __restrict__ dtraw,
                         float* __restrict__ consts) {
  __shared__ float mx[256];
  const int t = threadIdx.x;
  const ushort_t* e = (const ushort_t*)eps;
  float m = 0.f;
#pragma unroll
  for (int k = 0; k < 4; ++k) {
    float v = fabsf(bf2f(e[t * 4 + k]));
    if (!(v < 1e30f)) v = 1e30f;
    m = fmaxf(m, v);
  }
  mx[t] = m;
  __syncthreads();
  if (t == 0) {
    float M = 0.f;
    for (int k = 0; k < 256; ++k) M = fmaxf(M, mx[k]);
    const int f32 = (M > 1e3f) ? 1 : 0;
    float dt;
    if (f32) {
      dt = *(const float*)dtraw;
    } else {
      float db = bf2f(*(const ushort_t*)dtraw);
      float df = *(const float*)dtraw;
      dt = (db > 1e-6f && db < 1e3f) ? db : df;
    }
    const float h = dt * 0.125f;
    consts[0] = h;
    consts[1] = sqrtf(fabsf(h) + 1e-8f);
    consts[2] = dt;
    consts[3] = (float)f32;
  }
}

// one-time: convert weights to bf16 canon: [W1 | Wd1 | W2 | W3 | Wd2]
struct ConvArgs { const void* src[5]; };
#define CONV_TOT 2621440

__global__ void k_conv(ConvArgs a, const float* __restrict__ consts,
                       ushort_t* __restrict__ base) {
  constexpr int CUM[6] = {0, 524288, 786432, 1835008, 2359296, 2621440};
  const int f32 = consts[3] != 0.f;
  const int i = (blockIdx.x * 256 + threadIdx.x) * 4;
  if (i >= CONV_TOT) return;
  int j = 0;
#pragma unroll
  for (int k = 1; k < 5; ++k)
    if (i >= CUM[k]) j = k;
  const int local = i - CUM[j];
  const void* s = a.src[j];
  ushort4 o;
  if (f32) {
    float4 v = ((const float4*)s)[local >> 2];
    o = make_ushort4(f2bf(v.x), f2bf(v.y), f2bf(v.z), f2bf(v.w));
  } else {
    o = ((const ushort4*)s)[local >> 2];
  }
  *(ushort4*)(base + i) = o;
}

// ---------------------------------------------------------------------------
// Generic MFMA GEMM body. BM = MT*64, BN=64 (NT=4), BK=64, 256 threads.
// DEEP=0: 2-buffer SINGLE-barrier pipeline (stage-after-barrier).
// DEEP=1: 3-buffer 2-tile-deep pipeline, one barrier/iter (fupd).
// Source+read XOR swizzle -> conflict-free ds_read. LPT = MT*2+2.
// MODE 0 plain, 1 tanh, 2 softplus+1e-5. BIAS: add bias[gn+ncol0].
// STATS: per-col sum/sumsq -> s1/s2 atomics (sS shared float[128]).
// FUSE: Euler update epilogue. FINAL: also out0 = z_new + Ub.
// ANORM: A passes through relu(x*sc+sh); sc/sh in fp16 LDS tables (4KB).
// ---------------------------------------------------------------------------
template <int MT, int KT, int MODE, int STATS, int FUSE, int BIAS, int FINAL,
          int ANORM, int DEEP>
__device__ __forceinline__ void gemm_body(
    const ushort_t* __restrict__ A, const ushort_t* __restrict__ W,
    const void* __restrict__ bias, int ncol0, ushort_t* __restrict__ Cout,
    int Nout, int m0, int n0, __bf16* As, __bf16* Bs,
    float* __restrict__ s1, float* __restrict__ s2,
    const ushort_t* __restrict__ Gb, float* __restrict__ zf,
    ushort_t* __restrict__ zb, const void* __restrict__ eps,
    unsigned long long eoff, const float* __restrict__ consts,
    const float* __restrict__ Ub, float* __restrict__ out0,
    const float* __restrict__ s1in, const float* __restrict__ s2in,
    const void* __restrict__ gsc, const void* __restrict__ gbe,
    _Float16* scF, _Float16* shF, float* sS) {
  constexpr int BM = MT * 64;
  constexpr int LPT = MT * 2 + 2;  // global_load_lds per wave per tile
  const int f32 = consts[3] != 0.f;
  const int tid = threadIdx.x;
  const int lane = tid & 63;
  const int wave = tid >> 6;
  const int col = lane & 15;
  const int quad = lane >> 4;
  const int rowBase = wave * (MT * 16);

  // staging: 16B per lane, source-side XOR swizzle (both-sides rule)
  const int srow = tid >> 3;
  const int skc = tid & 7;
  auto stageA = [&](int k0, __bf16* dst) {
#pragma unroll
    for (int j = 0; j < BM / 32; ++j) {
      const int row = j * 32 + srow;
      async16(A + (size_t)(m0 + row) * KT + k0 + (((skc ^ (row & 7))) << 3),
              (char*)dst + (j * 256 + tid) * 16);
    }
  };
  auto stageB = [&](int k0, __bf16* dst) {
#pragma unroll
    for (int j = 0; j < 2; ++j) {
      const int row = j * 32 + srow;
      async16(W + (size_t)(n0 + row) * KT + k0 + (((skc ^ (row & 7))) << 3),
              (char*)dst + (j * 256 + tid) * 16);
    }
  };

  auto tables = [&]() {
    if (ANORM) {
      const float inv = 1.0f / 4096.0f;
#pragma unroll
      for (int c0 = 0; c0 < KT; c0 += 256) {
        const int c = c0 + tid;
        float mu = s1in[c] * inv;
        float var = fmaxf(s2in[c] * inv - mu * mu, 0.f);
        float sc = ldin(gsc, c, f32) * rsqrtf(var + 1e-5f);
        scF[c] = (_Float16)sc;
        shF[c] = (_Float16)(ldin(gbe, c, f32) - mu * sc);
      }
    }
  };

  f32x4 acc[MT][4] = {};
  constexpr int NIT = KT / 64;

  auto computeTile = [&](const __bf16* Ac, const __bf16* Bc, int k0) {
#pragma unroll
    for (int kk = 0; kk < 2; ++kk) {
      const int kb = kk * 32 + quad * 8;
      bf16x8 af[MT], bfr[4];
      if (ANORM) {
        f16x8 scv = *(const f16x8*)&scF[k0 + kb];
        f16x8 shv = *(const f16x8*)&shF[k0 + kb];
#pragma unroll
        for (int mt = 0; mt < MT; ++mt) {
          bf16x8 raw = lds_frag(Ac, rowBase + mt * 16 + col, kb);
#pragma unroll
          for (int j = 0; j < 8; ++j)
            af[mt][j] = (__bf16)fmaxf(
                fmaf((float)raw[j], (float)scv[j], (float)shv[j]), 0.f);
        }
      } else {
#pragma unroll
        for (int mt = 0; mt < MT; ++mt)
          af[mt] = lds_frag(Ac, rowBase + mt * 16 + col, kb);
      }
#pragma unroll
      for (int nt = 0; nt < 4; ++nt)
        bfr[nt] = lds_frag(Bc, nt * 16 + col, kb);
      __builtin_amdgcn_s_setprio(1);
#pragma unroll
      for (int mt = 0; mt < MT; ++mt)
#pragma unroll
        for (int nt = 0; nt < 4; ++nt)
          acc[mt][nt] = __builtin_amdgcn_mfma_f32_16x16x32_bf16(
              af[mt], bfr[nt], acc[mt][nt], 0, 0, 0);
      __builtin_amdgcn_s_setprio(0);
    }
  };

  if (DEEP) {
    // 3-buffer, 2 tiles in flight, one barrier per iter (r24 proven).
    __bf16* Ac = As;
    __bf16* An = As + BM * 64;
    __bf16* A2 = As + 2 * BM * 64;
    __bf16* Bc = Bs;
    __bf16* Bn = Bs + 64 * 64;
    __bf16* B2 = Bs + 2 * 64 * 64;
    stageA(0, Ac);
    stageB(0, Bc);
    stageA(64, An);
    stageB(64, Bn);
    tables();
    waitlgkm0();  // table ds_writes retired; iter-0 barrier publishes
#pragma unroll 1
    for (int it = 0; it < NIT; ++it) {
      if (it + 1 < NIT) {
        waitvm<LPT>();  // tile it landed; tile it+1 still flying
      } else {
        waitvm<0>();
      }
      __builtin_amdgcn_s_barrier();  // tile it (and tables) visible;
                                     // all waves consumed iter it-1 reads
      if (it + 2 < NIT) {
        stageA((it + 2) * 64, A2);   // A2 was read at iter it-1: safe
        stageB((it + 2) * 64, B2);
      }
      computeTile(Ac, Bc, it * 64);
      __bf16* ta = Ac; Ac = An; An = A2; A2 = ta;
      __bf16* tb = Bc; Bc = Bn; Bn = B2; B2 = tb;
    }
  } else {
    // 2-buffer SINGLE-barrier pipeline: waitvm(0) -> barrier ->
    // stage(it+1 into alt) -> compute(cur). Alt is dead at stage time
    // (all waves' reads of it retired before they reached this barrier).
    __bf16* Acur = As;
    __bf16* Aalt = As + BM * 64;
    __bf16* Bcur = Bs;
    __bf16* Balt = Bs + 64 * 64;
    stageA(0, Acur);
    stageB(0, Bcur);
    tables();
    waitlgkm0();  // table ds_writes retired; iter-0 barrier publishes
#pragma unroll 1
    for (int it = 0; it < NIT; ++it) {
      waitvm<0>();                   // this wave's tile-it loads landed
      __builtin_amdgcn_s_barrier();  // all waves waited; prev reads done
      if (it + 1 < NIT) {
        stageA((it + 1) * 64, Aalt);
        stageB((it + 1) * 64, Balt);
      }
      computeTile(Acur, Bcur, it * 64);
      __bf16* t0 = Acur; Acur = Aalt; Aalt = t0;
      __bf16* t1 = Bcur; Bcur = Balt; Balt = t1;
    }
  }

  if (STATS) {
    for (int i = tid; i < 128; i += 256) sS[i] = 0.f;
    __syncthreads();
  }

  const float h = consts[0], sh = consts[1];

#pragma unroll
  for (int nt = 0; nt < 4; ++nt) {
    const int gn = n0 + nt * 16 + col;
    const float bv = BIAS ? ldin(bias, gn + ncol0, f32) : 0.f;
    float ls = 0.f, lq = 0.f;
#pragma unroll
    for (int mt = 0; mt < MT; ++mt) {
#pragma unroll
      for (int r = 0; r < 4; ++r) {
        const int gm = m0 + rowBase + mt * 16 + quad * 4 + r;
        float v = acc[mt][nt][r] + bv;
        if (STATS) {
          ls += v;
          lq += v * v;
        }
        if (MODE == 1) {
          v = tanhf(v);
        } else if (MODE == 2) {
          v = fmaxf(v, 0.f) + log1pf(expf(-fabsf(v))) + 1e-5f;
        }
        const size_t o = (size_t)gm * Nout + gn + ncol0;
        if (FUSE) {
          const float e = ldin(eps, eoff + o, f32);
          const float g = bf2f(Gb[o]);
          const float z = zf[o] + h * v + sh * g * e;
          zf[o] = z;
          zb[o] = f2bf(z);
          if (FINAL) out0[o] = z + Ub[o];
        } else {
          Cout[o] = f2bf(v);
        }
      }
    }
    if (STATS) {
      atomicAdd(&sS[nt * 16 + col], ls);
      atomicAdd(&sS[64 + nt * 16 + col], lq);
    }
  }

  if (STATS) {
    __syncthreads();
    if (tid < 64) {
      atomicAdd(&s1[n0 + tid], sS[tid]);
      atomicAdd(&s2[n0 + tid], sS[64 + tid]);
    }
  }
}

// X1 raw (stats) merged with T=tanh. W = W1||Wd1 (1536 rows, K=512).
// 768 blocks: 32 m-blocks x 24 n-strips (n<16 -> X1/stats, else T=tanh).
__global__ __launch_bounds__(256, 3) void k_x1t(
    const ushort_t* __restrict__ zb, const ushort_t* __restrict__ Wcat,
    const void* __restrict__ bd1, ushort_t* __restrict__ Xb,
    ushort_t* __restrict__ Tb, float* __restrict__ s1, float* __restrict__ s2,
    const float* __restrict__ consts) {
  __shared__ __bf16 As[2 * 128 * 64] __attribute__((aligned(16)));
  __shared__ __bf16 Bs[2 * 64 * 64] __attribute__((aligned(16)));
  __shared__ float sS[128];
  const int L = blockIdx.x;            // 0..767
  const int q = L & 7, w = L >> 3;
  const int mloc = w & 3, n = w >> 2;  // 4 m-blocks x 24 n-strips
  const int m0 = (q * 4 + mloc) * 128;
  const int n0 = n * 64;
  if (n < 16) {
    gemm_body<2, 512, 0, 1, 0, 0, 0, 0, 0>(
        zb, Wcat, nullptr, 0, Xb, 1024, m0, n0, As, Bs, s1, s2, nullptr,
        nullptr, nullptr, nullptr, 0, consts, nullptr, nullptr, nullptr,
        nullptr, nullptr, nullptr, nullptr, nullptr, sS);
  } else {
    // W rows 1024..1535 of Wcat (n0 = n*64 >= 1024); output columns
    // shifted into Tb via ncol0 = -1024.
    gemm_body<2, 512, 1, 0, 0, 1, 0, 0, 0>(
        zb, Wcat, bd1, -1024, Tb, 512, m0, n0, As, Bs, nullptr,
        nullptr, nullptr, nullptr, nullptr, nullptr, 0, consts, nullptr,
        nullptr, nullptr, nullptr, nullptr, nullptr, nullptr, nullptr, sS);
  }
}

// X2 raw (stats2, A=bn(X1raw) on the fly) packed with G=softplus(T@Wd2+bd2).
// 768 blocks: [0,512) X2 (32m x 16n, MT=2), [512,768) G (32m x 8n, MT=2).
// LDS 52.7KB -> 3 blocks/CU; grid 768 = exactly 3/CU * 256.
__global__ __launch_bounds__(256, 3) void k_x2g(
    const ushort_t* __restrict__ X1raw, const ushort_t* __restrict__ W2c,
    const ushort_t* __restrict__ Tb, const ushort_t* __restrict__ Wd2c,
    const void* __restrict__ bd2, ushort_t* __restrict__ Ab,
    ushort_t* __restrict__ Gb, float* __restrict__ s1o, float* __restrict__ s2o,
    const float* __restrict__ s1i, const float* __restrict__ s2i,
    const void* __restrict__ g1, const void* __restrict__ be1,
    const float* __restrict__ consts) {
  __shared__ __bf16 As[2 * 128 * 64] __attribute__((aligned(16)));
  __shared__ __bf16 Bs[2 * 64 * 64] __attribute__((aligned(16)));
  __shared__ _Float16 scF[1024] __attribute__((aligned(16)));
  __shared__ _Float16 shF[1024] __attribute__((aligned(16)));
  __shared__ float sS[128];
  const int L = blockIdx.x;
  if (L < 512) {
    const int q = L & 7, w = L >> 3;
    const int mloc = w & 3, n = w >> 2;  // 4 m-blocks x 16 n-strips
    const int m0 = (q * 4 + mloc) * 128, n0 = n * 64;
    gemm_body<2, 1024, 0, 1, 0, 0, 0, 1, 0>(
        X1raw, W2c, nullptr, 0, Ab, 1024, m0, n0, As, Bs, s1o, s2o,
        nullptr, nullptr, nullptr, nullptr, 0, consts, nullptr, nullptr, s1i,
        s2i, g1, be1, scF, shF, sS);
  } else {
    const int Lg = L - 512;
    const int q = Lg & 7, w = Lg >> 3;   // w 0..31
    const int mloc = w & 3, n = w >> 2;  // 4 m-blocks x 8 n-strips
    const int m0 = (q * 4 + mloc) * 128, n0 = n * 64;
    gemm_body<2, 512, 2, 0, 0, 1, 0, 0, 0>(
        Tb, Wd2c, bd2, 0, Gb, 512, m0, n0, As, Bs, nullptr, nullptr,
        nullptr, nullptr, nullptr, nullptr, 0, consts, nullptr, nullptr,
        nullptr, nullptr, nullptr, nullptr, nullptr, nullptr, sS);
  }
}

// F = bn(X2raw)@W3^T + b3 (A-norm on the fly) with fused Euler update.
// 512 blocks: 64 m-blocks (MT=1) x 8 n-strips. Grid-limited to 2 blk/CU;
// DEEP=1 3-buffer pipeline, LDS 52KB (3/CU capacity, no occupancy cost).
template <int FINAL>
__global__ __launch_bounds__(256, 2) void k_fupd(
    const ushort_t* __restrict__ X2raw, const ushort_t* __restrict__ W3c,
    const void* __restrict__ b3, const ushort_t* __restrict__ Gb,
    float* __restrict__ zf, ushort_t* __restrict__ zb,
    const void* __restrict__ eps, unsigned long long eoff,
    const float* __restrict__ consts, const float* __restrict__ Ub,
    float* __restrict__ out0, const float* __restrict__ s1i,
    const float* __restrict__ s2i, const void* __restrict__ g2,
    const void* __restrict__ be2) {
  __shared__ __bf16 As[3 * 64 * 64] __attribute__((aligned(16)));
  __shared__ __bf16 Bs[3 * 64 * 64] __attribute__((aligned(16)));
  __shared__ _Float16 scF[1024] __attribute__((aligned(16)));
  __shared__ _Float16 shF[1024] __attribute__((aligned(16)));
  const int L = blockIdx.x;            // 0..511
  const int q = L & 7, w = L >> 3;
  const int mloc = w & 7, n = w >> 3;  // 8 m-blocks x 8 n-strips
  const int m0 = (q * 8 + mloc) * 64, n0 = n * 64;
  gemm_body<1, 1024, 0, 0, 1, 1, FINAL, 1, 1>(
      X2raw, W3c, b3, 0, nullptr, 512, m0, n0, As, Bs, nullptr, nullptr,
      Gb, zf, zb, eps, eoff, consts, Ub, out0, s1i, s2i, g2, be2, scF, shF,
      nullptr);
}

// zf (fp32 master) + zb (bf16 shadow) <- z_dyn
__global__ void k_init(const void* __restrict__ z, float* __restrict__ zf,
                       ushort_t* __restrict__ zb, const float* __restrict__ consts) {
  const int f32 = consts[3] != 0.f;
  const int i = blockIdx.x * 256 + threadIdx.x;
  float4 v;
  if (f32) {
    v = ((const float4*)z)[i];
  } else {
    ushort4 u = ((const ushort4*)z)[i];
    v = make_float4(bf2f(u.x), bf2f(u.y), bf2f(u.z), bf2f(u.w));
  }
  ((float4*)zf)[i] = v;
  ((ushort4*)zb)[i] = make_ushort4(f2bf(v.x), f2bf(v.y), f2bf(v.z), f2bf(v.w));
}

// Ub = dt*(ut@Bsde^T), fp32 (4096x512), LDS-tiled 64x64 K=64
__global__ __launch_bounds__(256) void k_ub(
    const void* __restrict__ ut, const void* __restrict__ Bsde,
    const float* __restrict__ consts, float* __restrict__ Ub) {
  __shared__ float As[64][68];
  __shared__ float Bs[64][68];
  const float dt = consts[2];
  const int f32 = consts[3] != 0.f;
  const int t = threadIdx.x;
  const int tx = t & 15, ty = t >> 4;
  const int n0 = blockIdx.x * 64, m0 = blockIdx.y * 64;
  const int r = t >> 2;
  const int c0 = (t & 3) * 16;

#pragma unroll
  for (int j = 0; j < 16; ++j) {
    As[c0 + j][r] = ldin(ut, (size_t)(m0 + r) * 64 + c0 + j, f32);
    Bs[c0 + j][r] = ldin(Bsde, (size_t)(n0 + r) * 64 + c0 + j, f32);
  }
  __syncthreads();

  float acc[4][4] = {};
#pragma unroll 8
  for (int kk = 0; kk < 64; ++kk) {
    float a[4], b[4];
    *(float4*)a = *(const float4*)&As[kk][ty * 4];
    *(float4*)b = *(const float4*)&Bs[kk][tx * 4];
#pragma unroll
    for (int i = 0; i < 4; ++i)
#pragma unroll
      for (int j = 0; j < 4; ++j) acc[i][j] += a[i] * b[j];
  }

#pragma unroll
  for (int i = 0; i < 4; ++i) {
    const size_t o = (size_t)(m0 + ty * 4 + i) * 512 + n0 + tx * 4;
    *(float4*)&Ub[o] = make_float4(dt * acc[i][0], dt * acc[i][1],
                                   dt * acc[i][2], dt * acc[i][3]);
  }
}

// Deff[j][k] = D[j][k] + sum_l C[j][l]*Bsde[l][k]  (25x64)
__global__ void k_deff(const void* __restrict__ Cm, const void* __restrict__ Bsde,
                       const void* __restrict__ Dm, const float* __restrict__ consts,
                       float* __restrict__ Deff) {
  __shared__ float red[4][64];
  const int f32 = consts[3] != 0.f;
  const int j = blockIdx.x;
  const int k = threadIdx.x & 63;
  const int part = threadIdx.x >> 6;
  float acc = 0.f;
  const int l0 = part * 128;
#pragma unroll 8
  for (int l = l0; l < l0 + 128; ++l)
    acc += ldin(Cm, (size_t)j * 512 + l, f32) * ldin(Bsde, (size_t)l * 64 + k, f32);
  red[part][k] = acc;
  __syncthreads();
  if (part == 0) {
    float s = red[0][k] + red[1][k] + red[2][k] + red[3][k];
    Deff[j * 64 + k] = s + ldin(Dm, (size_t)j * 64 + k, f32);
  }
}

// yt = zf@C^T + dt*(ut@Deff^T): wave-per-row
__global__ __launch_bounds__(256) void k_final2(
    const float* __restrict__ zf, const void* __restrict__ ut,
    const float* __restrict__ consts, const void* __restrict__ Cm,
    const float* __restrict__ Deff, float* __restrict__ out1) {
  const float dt = consts[2];
  const int f32 = consts[3] != 0.f;
  const int t = threadIdx.x;
  const int lane = t & 63;
  const int m = blockIdx.x * 4 + (t >> 6);
  float z8[8];
#pragma unroll
  for (int i = 0; i < 8; ++i) z8[i] = zf[(size_t)m * 512 + i * 64 + lane];
  const float u = ldin(ut, (size_t)m * 64 + lane, f32);

  for (int j = 0; j < 25; ++j) {
    float p = dt * u * Deff[j * 64 + lane];
#pragma unroll
    for (int i = 0; i < 8; ++i)
      p += z8[i] * ldin(Cm, (size_t)j * 512 + i * 64 + lane, f32);
#pragma unroll
    for (int off = 32; off > 0; off >>= 1) p += __shfl_down(p, off, 64);
    if (lane == 0) out1[m * 25 + j] = p;
  }
}

// ---------------------------------------------------------------------------
extern "C" void kernel_launch(void* const* d_in, const int* in_sizes, int n_in,
                              void* d_out, int out_size, void* d_ws, size_t ws_size,
                              hipStream_t stream) {
  static const int expA[22] = {
      2097152, 524288, 1,      262144, 16777216, 524288, 1024, 1024,
      1024,    1048576, 1024,  1024,   1024,     524288, 512,  262144,
      512,     262144, 512,    32768,  12800,    1600};

  int map[21];
  bool okA = (n_in == 22), okB = (n_in == 21);
  if (okA)
    for (int i = 0; i < 22; ++i)
      if (in_sizes[i] != expA[i]) { okA = false; break; }
  if (okB) {
    int j = 0;
    for (int i = 0; i < 22; ++i) {
      if (i == 1) continue;
      if (in_sizes[j] != expA[i]) { okB = false; break; }
      ++j;
    }
  }
  if (okA) {
    map[0] = 0;
    for (int i = 1; i < 21; ++i) map[i] = i + 1;
  } else if (okB) {
    for (int i = 0; i < 21; ++i) map[i] = i;
  } else {
    map[0] = 0;
    for (int i = 1; i < 21; ++i) map[i] = (i + 1 < n_in) ? i + 1 : n_in - 1;
  }

  const void* z_dyn = d_in[map[0]];
  const void* dtp = d_in[map[1]];
  const void* ut = d_in[map[2]];
  const void* eps = d_in[map[3]];
  const void* W1 = d_in[map[4]];
  const void* g1 = d_in[map[6]];
  const void* be1 = d_in[map[7]];
  const void* W2 = d_in[map[8]];
  const void* g2 = d_in[map[10]];
  const void* be2 = d_in[map[11]];
  const void* W3 = d_in[map[12]];
  const void* b3 = d_in[map[13]];
  const void* Wd1 = d_in[map[14]];
  const void* bd1 = d_in[map[15]];
  const void* Wd2 = d_in[map[16]];
  const void* bd2 = d_in[map[17]];
  const void* Bsde = d_in[map[18]];
  const void* Cm = d_in[map[19]];
  const void* Dm = d_in[map[20]];

  // ws layout (~50 MB of 268 MB):
  //  [0,8M) zf fp32; [8,12M) zb bf16
  //  [12,20M) Xb bf16 raw X1; [20,28M) Ab bf16 raw X2
  //  [28,32M) Tb bf16; [32,36M) Gb bf16; [36,44M) Ub fp32
  //  [44,49.25M) canon bf16 weights [W1|Wd1|W2|W3|Wd2]
  //  [49.5M) stats 16x2048 f32, consts, Deff
  char* ws = (char*)d_ws;
  const size_t MB = 1024 * 1024;
  float* zf = (float*)(ws + 0);
  ushort_t* zb = (ushort_t*)(ws + 8 * MB);
  ushort_t* Xb = (ushort_t*)(ws + 12 * MB);
  ushort_t* Ab = (ushort_t*)(ws + 20 * MB);
  ushort_t* Tb = (ushort_t*)(ws + 28 * MB);
  ushort_t* Gb = (ushort_t*)(ws + 32 * MB);
  float* Ub = (float*)(ws + 36 * MB);
  ushort_t* canon = (ushort_t*)(ws + 44 * MB);
  float* stats = (float*)(ws + 49 * MB + 512 * 1024);
  float* consts = stats + 16 * 2048;
  float* Deff = consts + 16;

  const ushort_t* Wcat = canon + 0;
  const ushort_t* W2c = canon + 786432;
  const ushort_t* W3c = canon + 1835008;
  const ushort_t* Wd2c = canon + 2359296;

  float* out_z = (float*)d_out;
  float* out_y = out_z + 4096 * 512;

  const dim3 blk(256);

  k_detect<<<1, blk, 0, stream>>>(eps, dtp, consts);

  ConvArgs ca;
  ca.src[0] = W1;
  ca.src[1] = Wd1;
  ca.src[2] = W2;
  ca.src[3] = W3;
  ca.src[4] = Wd2;
  k_conv<<<(CONV_TOT / 4 + 255) / 256, blk, 0, stream>>>(ca, consts, canon);

  hipMemsetAsync(stats, 0, 16 * 2048 * sizeof(float), stream);
  k_init<<<2048, blk, 0, stream>>>(z_dyn, zf, zb, consts);
  k_ub<<<dim3(8, 64), blk, 0, stream>>>(ut, Bsde, consts, Ub);
  k_deff<<<25, blk, 0, stream>>>(Cm, Bsde, Dm, consts, Deff);

  for (int s = 0; s < 8; ++s) {
    float* sA1 = stats + (s * 2 + 0) * 2048;
    float* sA2 = stats + (s * 2 + 1) * 2048;
    const unsigned long long eoff = (unsigned long long)s * 4096 * 512;

    // X1 raw (stats1) || T = tanh(z@Wd1^T+bd1)
    k_x1t<<<768, blk, 0, stream>>>(zb, Wcat, bd1, Xb, Tb,
                                   sA1, sA1 + 1024, consts);

    // X2 raw (stats2; A = relu(bn(X1raw)) on-the-fly) || G = softplus(...)
    k_x2g<<<768, blk, 0, stream>>>(Xb, W2c, Tb, Wd2c, bd2, Ab, Gb,
                                   sA2, sA2 + 1024, sA1, sA1 + 1024,
                                   g1, be1, consts);

    // F = relu(bn(X2raw))@W3^T + b3, fused z += h*F + sh*G*eps
    if (s < 7) {
      k_fupd<0><<<512, blk, 0, stream>>>(Ab, W3c, b3, Gb, zf, zb, eps, eoff,
                                         consts, Ub, out_z, sA2, sA2 + 1024,
                                         g2, be2);
    } else {
      k_fupd<1><<<512, blk, 0, stream>>>(Ab, W3c, b3, Gb, zf, zb, eps, eoff,
                                         consts, Ub, out_z, sA2, sA2 + 1024,
                                         g2, be2);
    }
  }

  k_final2<<<1024, blk, 0, stream>>>(zf, ut, consts, Cm, Deff, out_y);
}

// Round 12
// 750.616 us; speedup vs baseline: 1.0244x; 1.0244x over previous
//
#include <hip/hip_runtime.h>

// ---------------------------------------------------------------------------
// ConditionedLatentSDETransition - MI355X (round 26: r24 bodies + merged prep)
//
// r23=767 / r24=763 / r25=769 (noise band +-6): pipeline variants exhausted;
// x2g pipe audit: LDS-read ~50%, VALU ~38%, MFMA ~9% -> latency-bound at
// 3 waves/SIMD; B-frag read redundancy scales with waves so TLP can't fix.
// Remaining mechanism-backed cost: dispatch boundaries (30 x ~3-4us).
// This round: GEMM bodies exactly as r24 (best measured); prologue
// conv+init+ub+deff+stats-memset merged into ONE k_prep kernel
// (block-range dispatch; all depend only on k_detect's consts).
// 30 -> 26 dispatches, numerics byte-identical.
// ---------------------------------------------------------------------------

typedef unsigned short ushort_t;
typedef __bf16 bf16x8 __attribute__((ext_vector_type(8)));
typedef _Float16 f16x8 __attribute__((ext_vector_type(8)));
typedef float f32x4 __attribute__((ext_vector_type(4)));

__device__ __forceinline__ float bf2f(ushort_t s) {
  unsigned u = ((unsigned)s) << 16;
  return __uint_as_float(u);
}
__device__ __forceinline__ ushort_t f2bf(float f) {
  unsigned u = __float_as_uint(f);
  unsigned lsb = (u >> 16) & 1u;
  u += 0x7fffu + lsb;
  return (ushort_t)(u >> 16);
}
__device__ __forceinline__ float ldin(const void* p, size_t i, int f32) {
  return f32 ? ((const float*)p)[i] : bf2f(((const ushort_t*)p)[i]);
}
__device__ __forceinline__ void async16(const void* g, void* l) {
  __builtin_amdgcn_global_load_lds(
      (const __attribute__((address_space(1))) void*)g,
      (__attribute__((address_space(3))) void*)l, 16, 0, 0);
}

template <int N>
__device__ __forceinline__ void waitvm() {
  if constexpr (N == 0) {
    asm volatile("s_waitcnt vmcnt(0)" ::: "memory");
  } else if constexpr (N == 4) {
    asm volatile("s_waitcnt vmcnt(4)" ::: "memory");
  } else if constexpr (N == 6) {
    asm volatile("s_waitcnt vmcnt(6)" ::: "memory");
  }
  __builtin_amdgcn_sched_barrier(0);
}
__device__ __forceinline__ void waitlgkm0() {
  asm volatile("s_waitcnt lgkmcnt(0)" ::: "memory");
  __builtin_amdgcn_sched_barrier(0);
}

// Swizzled fragment read from a [rows][64] bf16 tile staged with source-side
// swizzle kc ^= (row&7). kb = bf16 offset in row, multiple of 8.
__device__ __forceinline__ bf16x8 lds_frag(const __bf16* T, int row, int kb) {
  const int byte = (row << 7) + ((((kb >> 3) ^ (row & 7))) << 4);
  return *(const bf16x8*)((const char*)T + byte);
}

// consts: [0]=h, [1]=sqrt_h, [2]=dt, [3]=f32flag
__global__ void k_detect(const void* __restrict__ eps, const void* __restrict__ dtraw,
                         float* __restrict__ consts) {
  __shared__ float mx[256];
  const int t = threadIdx.x;
  const ushort_t* e = (const ushort_t*)eps;
  float m = 0.f;
#pragma unroll
  for (int k = 0; k < 4; ++k) {
    float v = fabsf(bf2f(e[t * 4 + k]));
    if (!(v < 1e30f)) v = 1e30f;
    m = fmaxf(m, v);
  }
  mx[t] = m;
  __syncthreads();
  if (t == 0) {
    float M = 0.f;
    for (int k = 0; k < 256; ++k) M = fmaxf(M, mx[k]);
    const int f32 = (M > 1e3f) ? 1 : 0;
    float dt;
    if (f32) {
      dt = *(const float*)dtraw;
    } else {
      float db = bf2f(*(const ushort_t*)dtraw);
      float df = *(const float*)dtraw;
      dt = (db > 1e-6f && db < 1e3f) ? db : df;
    }
    const float h = dt * 0.125f;
    consts[0] = h;
    consts[1] = sqrtf(fabsf(h) + 1e-8f);
    consts[2] = dt;
    consts[3] = (float)f32;
  }
}

struct ConvArgs { const void* src[5]; };
#define CONV_TOT 2621440

// Merged prologue: [0,2560) weight-conv | [2560,4608) z-init |
// [4608,5120) Ub GEMM | [5120,5145) Deff | [5145,5177) stats-zero.
// All branches depend only on consts (k_detect). One dispatch vs five.
__global__ __launch_bounds__(256) void k_prep(
    ConvArgs a, const float* __restrict__ consts, ushort_t* __restrict__ canon,
    const void* __restrict__ z, float* __restrict__ zf,
    ushort_t* __restrict__ zb, const void* __restrict__ ut,
    const void* __restrict__ Bsde, float* __restrict__ Ub,
    const void* __restrict__ Cm, const void* __restrict__ Dm,
    float* __restrict__ Deff, float* __restrict__ stats) {
  __shared__ float smem[2 * 64 * 68];
  const int f32 = consts[3] != 0.f;
  const int b = blockIdx.x;
  const int t = threadIdx.x;

  if (b < 2560) {
    // weight conversion to bf16 canon [W1 | Wd1 | W2 | W3 | Wd2]
    constexpr int CUM[6] = {0, 524288, 786432, 1835008, 2359296, 2621440};
    const int i = (b * 256 + t) * 4;
    if (i >= CONV_TOT) return;
    int j = 0;
#pragma unroll
    for (int k = 1; k < 5; ++k)
      if (i >= CUM[k]) j = k;
    const int local = i - CUM[j];
    const void* s = a.src[j];
    ushort4 o;
    if (f32) {
      float4 v = ((const float4*)s)[local >> 2];
      o = make_ushort4(f2bf(v.x), f2bf(v.y), f2bf(v.z), f2bf(v.w));
    } else {
      o = ((const ushort4*)s)[local >> 2];
    }
    *(ushort4*)(canon + i) = o;
  } else if (b < 4608) {
    // zf (fp32 master) + zb (bf16 shadow) <- z_dyn
    const int i = (b - 2560) * 256 + t;
    float4 v;
    if (f32) {
      v = ((const float4*)z)[i];
    } else {
      ushort4 u = ((const ushort4*)z)[i];
      v = make_float4(bf2f(u.x), bf2f(u.y), bf2f(u.z), bf2f(u.w));
    }
    ((float4*)zf)[i] = v;
    ((ushort4*)zb)[i] =
        make_ushort4(f2bf(v.x), f2bf(v.y), f2bf(v.z), f2bf(v.w));
  } else if (b < 5120) {
    // Ub = dt*(ut@Bsde^T), fp32 (4096x512), LDS-tiled 64x64 K=64
    float(*As)[68] = (float(*)[68])smem;
    float(*Bs)[68] = (float(*)[68])(smem + 64 * 68);
    const float dt = consts[2];
    const int bb = b - 4608;
    const int n0 = (bb & 7) * 64, m0 = (bb >> 3) * 64;
    const int tx = t & 15, ty = t >> 4;
    const int r = t >> 2;
    const int c0 = (t & 3) * 16;
#pragma unroll
    for (int j = 0; j < 16; ++j) {
      As[c0 + j][r] = ldin(ut, (size_t)(m0 + r) * 64 + c0 + j, f32);
      Bs[c0 + j][r] = ldin(Bsde, (size_t)(n0 + r) * 64 + c0 + j, f32);
    }
    __syncthreads();
    float acc[4][4] = {};
#pragma unroll 8
    for (int kk = 0; kk < 64; ++kk) {
      float av[4], bv[4];
      *(float4*)av = *(const float4*)&As[kk][ty * 4];
      *(float4*)bv = *(const float4*)&Bs[kk][tx * 4];
#pragma unroll
      for (int i = 0; i < 4; ++i)
#pragma unroll
        for (int j = 0; j < 4; ++j) acc[i][j] += av[i] * bv[j];
    }
#pragma unroll
    for (int i = 0; i < 4; ++i) {
      const size_t o = (size_t)(m0 + ty * 4 + i) * 512 + n0 + tx * 4;
      *(float4*)&Ub[o] = make_float4(dt * acc[i][0], dt * acc[i][1],
                                     dt * acc[i][2], dt * acc[i][3]);
    }
  } else if (b < 5145) {
    // Deff[j][k] = D[j][k] + sum_l C[j][l]*Bsde[l][k]  (25x64)
    float(*red)[64] = (float(*)[64])smem;
    const int j = b - 5120;
    const int k = t & 63;
    const int part = t >> 6;
    float acc = 0.f;
    const int l0 = part * 128;
#pragma unroll 8
    for (int l = l0; l < l0 + 128; ++l)
      acc += ldin(Cm, (size_t)j * 512 + l, f32) *
             ldin(Bsde, (size_t)l * 64 + k, f32);
    red[part][k] = acc;
    __syncthreads();
    if (part == 0) {
      float s = red[0][k] + red[1][k] + red[2][k] + red[3][k];
      Deff[j * 64 + k] = s + ldin(Dm, (size_t)j * 64 + k, f32);
    }
  } else {
    // zero the 16x2048 stats block
    const int i = ((b - 5145) * 256 + t) * 4;
    *(float4*)&stats[i] = make_float4(0.f, 0.f, 0.f, 0.f);
  }
}

// ---------------------------------------------------------------------------
// Generic MFMA GEMM body. BM = MT*64, BN=64 (NT=4), BK=64, 256 threads.
// DEEP=0: 2-buffer counted-vmcnt pipeline (r24 proven).
// DEEP=1: 3-buffer 2-tile-deep pipeline, one barrier/iter (fupd).
// Source+read XOR swizzle -> conflict-free ds_read. LPT = MT*2+2.
// MODE 0 plain, 1 tanh, 2 softplus+1e-5. BIAS: add bias[gn+ncol0].
// STATS: per-col sum/sumsq -> s1/s2 atomics (sS shared float[128]).
// FUSE: Euler update epilogue. FINAL: also out0 = z_new + Ub.
// ANORM: A passes through relu(x*sc+sh); sc/sh in fp16 LDS tables (4KB).
// ---------------------------------------------------------------------------
template <int MT, int KT, int MODE, int STATS, int FUSE, int BIAS, int FINAL,
          int ANORM, int DEEP>
__device__ __forceinline__ void gemm_body(
    const ushort_t* __restrict__ A, const ushort_t* __restrict__ W,
    const void* __restrict__ bias, int ncol0, ushort_t* __restrict__ Cout,
    int Nout, int m0, int n0, __bf16* As, __bf16* Bs,
    float* __restrict__ s1, float* __restrict__ s2,
    const ushort_t* __restrict__ Gb, float* __restrict__ zf,
    ushort_t* __restrict__ zb, const void* __restrict__ eps,
    unsigned long long eoff, const float* __restrict__ consts,
    const float* __restrict__ Ub, float* __restrict__ out0,
    const float* __restrict__ s1in, const float* __restrict__ s2in,
    const void* __restrict__ gsc, const void* __restrict__ gbe,
    _Float16* scF, _Float16* shF, float* sS) {
  constexpr int BM = MT * 64;
  constexpr int LPT = MT * 2 + 2;  // global_load_lds per wave per tile
  const int f32 = consts[3] != 0.f;
  const int tid = threadIdx.x;
  const int lane = tid & 63;
  const int wave = tid >> 6;
  const int col = lane & 15;
  const int quad = lane >> 4;
  const int rowBase = wave * (MT * 16);

  // staging: 16B per lane, source-side XOR swizzle (both-sides rule)
  const int srow = tid >> 3;
  const int skc = tid & 7;
  auto stageA = [&](int k0, __bf16* dst) {
#pragma unroll
    for (int j = 0; j < BM / 32; ++j) {
      const int row = j * 32 + srow;
      async16(A + (size_t)(m0 + row) * KT + k0 + (((skc ^ (row & 7))) << 3),
              (char*)dst + (j * 256 + tid) * 16);
    }
  };
  auto stageB = [&](int k0, __bf16* dst) {
#pragma unroll
    for (int j = 0; j < 2; ++j) {
      const int row = j * 32 + srow;
      async16(W + (size_t)(n0 + row) * KT + k0 + (((skc ^ (row & 7))) << 3),
              (char*)dst + (j * 256 + tid) * 16);
    }
  };

  auto tables = [&]() {
    if (ANORM) {
      const float inv = 1.0f / 4096.0f;
#pragma unroll
      for (int c0 = 0; c0 < KT; c0 += 256) {
        const int c = c0 + tid;
        float mu = s1in[c] * inv;
        float var = fmaxf(s2in[c] * inv - mu * mu, 0.f);
        float sc = ldin(gsc, c, f32) * rsqrtf(var + 1e-5f);
        scF[c] = (_Float16)sc;
        shF[c] = (_Float16)(ldin(gbe, c, f32) - mu * sc);
      }
    }
  };

  f32x4 acc[MT][4] = {};
  constexpr int NIT = KT / 64;

  auto computeTile = [&](const __bf16* Ac, const __bf16* Bc, int k0) {
#pragma unroll
    for (int kk = 0; kk < 2; ++kk) {
      const int kb = kk * 32 + quad * 8;
      bf16x8 af[MT], bfr[4];
      if (ANORM) {
        f16x8 scv = *(const f16x8*)&scF[k0 + kb];
        f16x8 shv = *(const f16x8*)&shF[k0 + kb];
#pragma unroll
        for (int mt = 0; mt < MT; ++mt) {
          bf16x8 raw = lds_frag(Ac, rowBase + mt * 16 + col, kb);
#pragma unroll
          for (int j = 0; j < 8; ++j)
            af[mt][j] = (__bf16)fmaxf(
                fmaf((float)raw[j], (float)scv[j], (float)shv[j]), 0.f);
        }
      } else {
#pragma unroll
        for (int mt = 0; mt < MT; ++mt)
          af[mt] = lds_frag(Ac, rowBase + mt * 16 + col, kb);
      }
#pragma unroll
      for (int nt = 0; nt < 4; ++nt)
        bfr[nt] = lds_frag(Bc, nt * 16 + col, kb);
      __builtin_amdgcn_s_setprio(1);
#pragma unroll
      for (int mt = 0; mt < MT; ++mt)
#pragma unroll
        for (int nt = 0; nt < 4; ++nt)
          acc[mt][nt] = __builtin_amdgcn_mfma_f32_16x16x32_bf16(
              af[mt], bfr[nt], acc[mt][nt], 0, 0, 0);
      __builtin_amdgcn_s_setprio(0);
    }
  };

  if (DEEP) {
    // 3-buffer, 2 tiles in flight, one barrier per iter (r24 proven).
    __bf16* Ac = As;
    __bf16* An = As + BM * 64;
    __bf16* A2 = As + 2 * BM * 64;
    __bf16* Bc = Bs;
    __bf16* Bn = Bs + 64 * 64;
    __bf16* B2 = Bs + 2 * 64 * 64;
    stageA(0, Ac);
    stageB(0, Bc);
    stageA(64, An);
    stageB(64, Bn);
    tables();
    waitlgkm0();  // table ds_writes retired; iter-0 barrier publishes
#pragma unroll 1
    for (int it = 0; it < NIT; ++it) {
      if (it + 1 < NIT) {
        waitvm<LPT>();  // tile it landed; tile it+1 still flying
      } else {
        waitvm<0>();
      }
      __builtin_amdgcn_s_barrier();  // tile it (and tables) visible;
                                     // all waves consumed iter it-1 reads
      if (it + 2 < NIT) {
        stageA((it + 2) * 64, A2);   // A2 was read at iter it-1: safe
        stageB((it + 2) * 64, B2);
      }
      computeTile(Ac, Bc, it * 64);
      __bf16* ta = Ac; Ac = An; An = A2; A2 = ta;
      __bf16* tb = Bc; Bc = Bn; Bn = B2; B2 = tb;
    }
  } else {
    // 2-buffer counted pipeline (r24 proven path).
    __bf16* Acur = As;
    __bf16* Aalt = As + BM * 64;
    __bf16* Bcur = Bs;
    __bf16* Balt = Bs + 64 * 64;
    stageA(0, Acur);
    stageB(0, Bcur);
    tables();
    waitlgkm0();                   // table ds_writes retired (no vm drain)
    __builtin_amdgcn_s_barrier();  // table visible to all waves
#pragma unroll 1
    for (int it = 0; it < NIT; ++it) {
      const int k0 = it * 64;
      if (it + 1 < NIT) {  // issue next tile; stays in flight across barrier
        stageA(k0 + 64, Aalt);
        stageB(k0 + 64, Balt);
        waitvm<LPT>();     // current tile landed; next tile still flying
      } else {
        waitvm<0>();       // last tile: drain
      }
      __builtin_amdgcn_s_barrier();  // readiness barrier
      computeTile(Acur, Bcur, k0);
      waitlgkm0();                   // this wave's ds_reads retired
      __builtin_amdgcn_s_barrier();  // safe for next iter to overwrite cur
      __bf16* t0 = Acur; Acur = Aalt; Aalt = t0;
      __bf16* t1 = Bcur; Bcur = Balt; Balt = t1;
    }
  }

  if (STATS) {
    for (int i = tid; i < 128; i += 256) sS[i] = 0.f;
    __syncthreads();
  }

  const float h = consts[0], sh = consts[1];

#pragma unroll
  for (int nt = 0; nt < 4; ++nt) {
    const int gn = n0 + nt * 16 + col;
    const float bv = BIAS ? ldin(bias, gn + ncol0, f32) : 0.f;
    float ls = 0.f, lq = 0.f;
#pragma unroll
    for (int mt = 0; mt < MT; ++mt) {
#pragma unroll
      for (int r = 0; r < 4; ++r) {
        const int gm = m0 + rowBase + mt * 16 + quad * 4 + r;
        float v = acc[mt][nt][r] + bv;
        if (STATS) {
          ls += v;
          lq += v * v;
        }
        if (MODE == 1) {
          v = tanhf(v);
        } else if (MODE == 2) {
          v = fmaxf(v, 0.f) + log1pf(expf(-fabsf(v))) + 1e-5f;
        }
        const size_t o = (size_t)gm * Nout + gn + ncol0;
        if (FUSE) {
          const float e = ldin(eps, eoff + o, f32);
          const float g = bf2f(Gb[o]);
          const float z = zf[o] + h * v + sh * g * e;
          zf[o] = z;
          zb[o] = f2bf(z);
          if (FINAL) out0[o] = z + Ub[o];
        } else {
          Cout[o] = f2bf(v);
        }
      }
    }
    if (STATS) {
      atomicAdd(&sS[nt * 16 + col], ls);
      atomicAdd(&sS[64 + nt * 16 + col], lq);
    }
  }

  if (STATS) {
    __syncthreads();
    if (tid < 64) {
      atomicAdd(&s1[n0 + tid], sS[tid]);
      atomicAdd(&s2[n0 + tid], sS[64 + tid]);
    }
  }
}

// X1 raw (stats) merged with T=tanh. W = W1||Wd1 (1536 rows, K=512).
// 768 blocks: 32 m-blocks x 24 n-strips (n<16 -> X1/stats, else T=tanh).
__global__ __launch_bounds__(256, 3) void k_x1t(
    const ushort_t* __restrict__ zb, const ushort_t* __restrict__ Wcat,
    const void* __restrict__ bd1, ushort_t* __restrict__ Xb,
    ushort_t* __restrict__ Tb, float* __restrict__ s1, float* __restrict__ s2,
    const float* __restrict__ consts) {
  __shared__ __bf16 As[2 * 128 * 64] __attribute__((aligned(16)));
  __shared__ __bf16 Bs[2 * 64 * 64] __attribute__((aligned(16)));
  __shared__ float sS[128];
  const int L = blockIdx.x;            // 0..767
  const int q = L & 7, w = L >> 3;
  const int mloc = w & 3, n = w >> 2;  // 4 m-blocks x 24 n-strips
  const int m0 = (q * 4 + mloc) * 128;
  const int n0 = n * 64;
  if (n < 16) {
    gemm_body<2, 512, 0, 1, 0, 0, 0, 0, 0>(
        zb, Wcat, nullptr, 0, Xb, 1024, m0, n0, As, Bs, s1, s2, nullptr,
        nullptr, nullptr, nullptr, 0, consts, nullptr, nullptr, nullptr,
        nullptr, nullptr, nullptr, nullptr, nullptr, sS);
  } else {
    // W rows 1024..1535 of Wcat (n0 = n*64 >= 1024); output columns
    // shifted into Tb via ncol0 = -1024.
    gemm_body<2, 512, 1, 0, 0, 1, 0, 0, 0>(
        zb, Wcat, bd1, -1024, Tb, 512, m0, n0, As, Bs, nullptr,
        nullptr, nullptr, nullptr, nullptr, nullptr, 0, consts, nullptr,
        nullptr, nullptr, nullptr, nullptr, nullptr, nullptr, nullptr, sS);
  }
}

// X2 raw (stats2, A=bn(X1raw) on the fly) packed with G=softplus(T@Wd2+bd2).
// 768 blocks: [0,512) X2 (32m x 16n, MT=2), [512,768) G (32m x 8n, MT=2).
// LDS 52.7KB -> 3 blocks/CU; grid 768 = exactly 3/CU * 256.
__global__ __launch_bounds__(256, 3) void k_x2g(
    const ushort_t* __restrict__ X1raw, const ushort_t* __restrict__ W2c,
    const ushort_t* __restrict__ Tb, const ushort_t* __restrict__ Wd2c,
    const void* __restrict__ bd2, ushort_t* __restrict__ Ab,
    ushort_t* __restrict__ Gb, float* __restrict__ s1o, float* __restrict__ s2o,
    const float* __restrict__ s1i, const float* __restrict__ s2i,
    const void* __restrict__ g1, const void* __restrict__ be1,
    const float* __restrict__ consts) {
  __shared__ __bf16 As[2 * 128 * 64] __attribute__((aligned(16)));
  __shared__ __bf16 Bs[2 * 64 * 64] __attribute__((aligned(16)));
  __shared__ _Float16 scF[1024] __attribute__((aligned(16)));
  __shared__ _Float16 shF[1024] __attribute__((aligned(16)));
  __shared__ float sS[128];
  const int L = blockIdx.x;
  if (L < 512) {
    const int q = L & 7, w = L >> 3;
    const int mloc = w & 3, n = w >> 2;  // 4 m-blocks x 16 n-strips
    const int m0 = (q * 4 + mloc) * 128, n0 = n * 64;
    gemm_body<2, 1024, 0, 1, 0, 0, 0, 1, 0>(
        X1raw, W2c, nullptr, 0, Ab, 1024, m0, n0, As, Bs, s1o, s2o,
        nullptr, nullptr, nullptr, nullptr, 0, consts, nullptr, nullptr, s1i,
        s2i, g1, be1, scF, shF, sS);
  } else {
    const int Lg = L - 512;
    const int q = Lg & 7, w = Lg >> 3;   // w 0..31
    const int mloc = w & 3, n = w >> 2;  // 4 m-blocks x 8 n-strips
    const int m0 = (q * 4 + mloc) * 128, n0 = n * 64;
    gemm_body<2, 512, 2, 0, 0, 1, 0, 0, 0>(
        Tb, Wd2c, bd2, 0, Gb, 512, m0, n0, As, Bs, nullptr, nullptr,
        nullptr, nullptr, nullptr, nullptr, 0, consts, nullptr, nullptr,
        nullptr, nullptr, nullptr, nullptr, nullptr, nullptr, sS);
  }
}

// F = bn(X2raw)@W3^T + b3 (A-norm on the fly) with fused Euler update.
// 512 blocks: 64 m-blocks (MT=1) x 8 n-strips. Grid-limited to 2 blk/CU;
// DEEP=1 3-buffer pipeline, LDS 52KB (3/CU capacity, no occupancy cost).
template <int FINAL>
__global__ __launch_bounds__(256, 2) void k_fupd(
    const ushort_t* __restrict__ X2raw, const ushort_t* __restrict__ W3c,
    const void* __restrict__ b3, const ushort_t* __restrict__ Gb,
    float* __restrict__ zf, ushort_t* __restrict__ zb,
    const void* __restrict__ eps, unsigned long long eoff,
    const float* __restrict__ consts, const float* __restrict__ Ub,
    float* __restrict__ out0, const float* __restrict__ s1i,
    const float* __restrict__ s2i, const void* __restrict__ g2,
    const void* __restrict__ be2) {
  __shared__ __bf16 As[3 * 64 * 64] __attribute__((aligned(16)));
  __shared__ __bf16 Bs[3 * 64 * 64] __attribute__((aligned(16)));
  __shared__ _Float16 scF[1024] __attribute__((aligned(16)));
  __shared__ _Float16 shF[1024] __attribute__((aligned(16)));
  const int L = blockIdx.x;            // 0..511
  const int q = L & 7, w = L >> 3;
  const int mloc = w & 7, n = w >> 3;  // 8 m-blocks x 8 n-strips
  const int m0 = (q * 8 + mloc) * 64, n0 = n * 64;
  gemm_body<1, 1024, 0, 0, 1, 1, FINAL, 1, 1>(
      X2raw, W3c, b3, 0, nullptr, 512, m0, n0, As, Bs, nullptr, nullptr,
      Gb, zf, zb, eps, eoff, consts, Ub, out0, s1i, s2i, g2, be2, scF, shF,
      nullptr);
}

// yt = zf@C^T + dt*(ut@Deff^T): wave-per-row
__global__ __launch_bounds__(256) void k_final2(
    const float* __restrict__ zf, const void* __restrict__ ut,
    const float* __restrict__ consts, const void* __restrict__ Cm,
    const float* __restrict__ Deff, float* __restrict__ out1) {
  const float dt = consts[2];
  const int f32 = consts[3] != 0.f;
  const int t = threadIdx.x;
  const int lane = t & 63;
  const int m = blockIdx.x * 4 + (t >> 6);
  float z8[8];
#pragma unroll
  for (int i = 0; i < 8; ++i) z8[i] = zf[(size_t)m * 512 + i * 64 + lane];
  const float u = ldin(ut, (size_t)m * 64 + lane, f32);

  for (int j = 0; j < 25; ++j) {
    float p = dt * u * Deff[j * 64 + lane];
#pragma unroll
    for (int i = 0; i < 8; ++i)
      p += z8[i] * ldin(Cm, (size_t)j * 512 + i * 64 + lane, f32);
#pragma unroll
    for (int off = 32; off > 0; off >>= 1) p += __shfl_down(p, off, 64);
    if (lane == 0) out1[m * 25 + j] = p;
  }
}

// ---------------------------------------------------------------------------
extern "C" void kernel_launch(void* const* d_in, const int* in_sizes, int n_in,
                              void* d_out, int out_size, void* d_ws, size_t ws_size,
                              hipStream_t stream) {
  static const int expA[22] = {
      2097152, 524288, 1,      262144, 16777216, 524288, 1024, 1024,
      1024,    1048576, 1024,  1024,   1024,     524288, 512,  262144,
      512,     262144, 512,    32768,  12800,    1600};

  int map[21];
  bool okA = (n_in == 22), okB = (n_in == 21);
  if (okA)
    for (int i = 0; i < 22; ++i)
      if (in_sizes[i] != expA[i]) { okA = false; break; }
  if (okB) {
    int j = 0;
    for (int i = 0; i < 22; ++i) {
      if (i == 1) continue;
      if (in_sizes[j] != expA[i]) { okB = false; break; }
      ++j;
    }
  }
  if (okA) {
    map[0] = 0;
    for (int i = 1; i < 21; ++i) map[i] = i + 1;
  } else if (okB) {
    for (int i = 0; i < 21; ++i) map[i] = i;
  } else {
    map[0] = 0;
    for (int i = 1; i < 21; ++i) map[i] = (i + 1 < n_in) ? i + 1 : n_in - 1;
  }

  const void* z_dyn = d_in[map[0]];
  const void* dtp = d_in[map[1]];
  const void* ut = d_in[map[2]];
  const void* eps = d_in[map[3]];
  const void* W1 = d_in[map[4]];
  const void* g1 = d_in[map[6]];
  const void* be1 = d_in[map[7]];
  const void* W2 = d_in[map[8]];
  const void* g2 = d_in[map[10]];
  const void* be2 = d_in[map[11]];
  const void* W3 = d_in[map[12]];
  const void* b3 = d_in[map[13]];
  const void* Wd1 = d_in[map[14]];
  const void* bd1 = d_in[map[15]];
  const void* Wd2 = d_in[map[16]];
  const void* bd2 = d_in[map[17]];
  const void* Bsde = d_in[map[18]];
  const void* Cm = d_in[map[19]];
  const void* Dm = d_in[map[20]];

  // ws layout (~50 MB of 268 MB):
  //  [0,8M) zf fp32; [8,12M) zb bf16
  //  [12,20M) Xb bf16 raw X1; [20,28M) Ab bf16 raw X2
  //  [28,32M) Tb bf16; [32,36M) Gb bf16; [36,44M) Ub fp32
  //  [44,49.25M) canon bf16 weights [W1|Wd1|W2|W3|Wd2]
  //  [49.5M) stats 16x2048 f32, consts, Deff
  char* ws = (char*)d_ws;
  const size_t MB = 1024 * 1024;
  float* zf = (float*)(ws + 0);
  ushort_t* zb = (ushort_t*)(ws + 8 * MB);
  ushort_t* Xb = (ushort_t*)(ws + 12 * MB);
  ushort_t* Ab = (ushort_t*)(ws + 20 * MB);
  ushort_t* Tb = (ushort_t*)(ws + 28 * MB);
  ushort_t* Gb = (ushort_t*)(ws + 32 * MB);
  float* Ub = (float*)(ws + 36 * MB);
  ushort_t* canon = (ushort_t*)(ws + 44 * MB);
  float* stats = (float*)(ws + 49 * MB + 512 * 1024);
  float* consts = stats + 16 * 2048;
  float* Deff = consts + 16;

  const ushort_t* Wcat = canon + 0;
  const ushort_t* W2c = canon + 786432;
  const ushort_t* W3c = canon + 1835008;
  const ushort_t* Wd2c = canon + 2359296;

  float* out_z = (float*)d_out;
  float* out_y = out_z + 4096 * 512;

  const dim3 blk(256);

  k_detect<<<1, blk, 0, stream>>>(eps, dtp, consts);

  ConvArgs ca;
  ca.src[0] = W1;
  ca.src[1] = Wd1;
  ca.src[2] = W2;
  ca.src[3] = W3;
  ca.src[4] = Wd2;

  // merged prologue: conv + init + Ub + Deff + stats-zero in one dispatch
  k_prep<<<5177, blk, 0, stream>>>(ca, consts, canon, z_dyn, zf, zb, ut,
                                   Bsde, Ub, Cm, Dm, Deff, stats);

  for (int s = 0; s < 8; ++s) {
    float* sA1 = stats + (s * 2 + 0) * 2048;
    float* sA2 = stats + (s * 2 + 1) * 2048;
    const unsigned long long eoff = (unsigned long long)s * 4096 * 512;

    // X1 raw (stats1) || T = tanh(z@Wd1^T+bd1)
    k_x1t<<<768, blk, 0, stream>>>(zb, Wcat, bd1, Xb, Tb,
                                   sA1, sA1 + 1024, consts);

    // X2 raw (stats2; A = relu(bn(X1raw)) on-the-fly) || G = softplus(...)
    k_x2g<<<768, blk, 0, stream>>>(Xb, W2c, Tb, Wd2c, bd2, Ab, Gb,
                                   sA2, sA2 + 1024, sA1, sA1 + 1024,
                                   g1, be1, consts);

    // F = relu(bn(X2raw))@W3^T + b3, fused z += h*F + sh*G*eps
    if (s < 7) {
      k_fupd<0><<<512, blk, 0, stream>>>(Ab, W3c, b3, Gb, zf, zb, eps, eoff,
                                         consts, Ub, out_z, sA2, sA2 + 1024,
                                         g2, be2);
    } else {
      k_fupd<1><<<512, blk, 0, stream>>>(Ab, W3c, b3, Gb, zf, zb, eps, eoff,
                                         consts, Ub, out_z, sA2, sA2 + 1024,
                                         g2, be2);
    }
  }

  k_final2<<<1024, blk, 0, stream>>>(zf, ut, consts, Cm, Deff, out_y);
}